// Round 13
// baseline (260.466 us; speedup 1.0000x reference)
//
#include <hip/hip_runtime.h>
#include <math.h>

#define N_NODES 8001
#define NPAD    8032      // 251*32, padded row count for attention operands
#define E_EDGES 160000
#define NQTOT   8064      // 63*128, query rows covered by attn grid
#define LOG2E   1.4426950408889634f
#define SP1     16        // key splits, layer 1 (D=128)
#define SP2     32        // key splits, layer 2 (D=64)

typedef unsigned short u16;
typedef __attribute__((ext_vector_type(8)))  short bf16x8;
typedef __attribute__((ext_vector_type(16))) float f32x16;

__device__ __forceinline__ short f2bf(float f) {
    unsigned u = __builtin_bit_cast(unsigned, f);
    u = (u + 0x7FFFu + ((u >> 16) & 1u)) >> 16;   // RNE
    return (short)u;
}
__device__ __forceinline__ float bf2f(u16 x) {
    return __builtin_bit_cast(float, (unsigned)x << 16);
}
// pack 2 f32 -> u32 of 2 bf16 (lo=a, hi=b), single instruction
__device__ __forceinline__ int pk2(float a, float b) {
    int r;
    asm("v_cvt_pk_bf16_f32 %0, %1, %2" : "=v"(r) : "v"(a), "v"(b));
    return r;
}

#define GLDS(g, l) __builtin_amdgcn_global_load_lds( \
    (const __attribute__((address_space(1))) void*)(g), \
    (__attribute__((address_space(3))) void*)(l), 16, 0, 0)

// ---------------------------------------------------------------------------
// Fused prep: blocks [0,625) edge-degree count; [625,2633) x -> bf16 cast;
// [2633,3945) all weight transposes (Q-slices scaled by log2e).
// ---------------------------------------------------------------------------
__global__ __launch_bounds__(256) void prep_all(
    const float* __restrict__ x, const int* __restrict__ ei,
    const float* __restrict__ Wq1, const float* __restrict__ Wk1,
    const float* __restrict__ Wv1, const float* __restrict__ Wg1,
    const float* __restrict__ Wq2, const float* __restrict__ Wk2,
    const float* __restrict__ Wv2, const float* __restrict__ Wg2,
    const float* __restrict__ Ws1, const float* __restrict__ Ws2,
    int* __restrict__ degi, u16* __restrict__ XB,
    u16* __restrict__ WT1, u16* __restrict__ WT2,
    u16* __restrict__ WST1, u16* __restrict__ WST2)
{
    const int b = blockIdx.x, tid = threadIdx.x;
    if (b < 625) {
        int e = b * 256 + tid;
        if (e < E_EDGES) atomicAdd(&degi[ei[E_EDGES + e]], 1);
    } else if (b < 2633) {            // cast x (K=512): 8 elems/thread
        size_t t = (size_t)(b - 625) * 256 + tid;
        int row = (int)(t / 64), c8 = (int)(t % 64) * 8;
        int lrow = min(row, N_NODES - 1);
        const float4* p = (const float4*)&x[(size_t)lrow * 512 + c8];
        float4 u = p[0], v = p[1];
        int4 w = { pk2(u.x, u.y), pk2(u.z, u.w), pk2(v.x, v.y), pk2(v.z, v.w) };
        *(int4*)&XB[t * 8] = w;
    } else if (b < 3657) {            // WT1 [4][128][512]
        int t = (b - 2633) * 256 + tid;
        int p = t / (128 * 512), n = (t / 512) & 127, k = t % 512;
        const float* W = (p == 0) ? Wq1 : (p == 1) ? Wk1 : (p == 2) ? Wv1 : Wg1;
        float v = W[k * 128 + n];
        if (p == 0) v *= LOG2E;
        WT1[t] = (u16)f2bf(v);
    } else if (b < 3785) {            // WT2 [4][64][128]
        int t = (b - 3657) * 256 + tid;
        int p = t / (64 * 128), n = (t / 128) & 63, k = t & 127;
        const float* W = (p == 0) ? Wq2 : (p == 1) ? Wk2 : (p == 2) ? Wv2 : Wg2;
        float v = W[k * 64 + n];
        if (p == 0) v *= LOG2E;
        WT2[t] = (u16)f2bf(v);
    } else if (b < 3913) {            // WST1 [128][256]
        int t = (b - 3785) * 256 + tid;
        int n = t >> 8, k = t & 255;
        WST1[t] = (u16)f2bf(Ws1[k * 128 + n]);
    } else {                          // WST2 [64][128]
        int t = (b - 3913) * 256 + tid;
        int n = t >> 7, k = t & 127;
        WST2[t] = (u16)f2bf(Ws2[k * 64 + n]);
    }
}

// ---------------------------------------------------------------------------
// MFMA fused 4-way projection (verified R7).
// ---------------------------------------------------------------------------
template<int K, int MOUT>
__global__ __launch_bounds__(256) void proj4_mfma(
    const u16* __restrict__ Xb, const u16* __restrict__ WT,
    const float* __restrict__ bq, const float* __restrict__ bk,
    const float* __restrict__ bv,
    u16* __restrict__ Qb, u16* __restrict__ Kb, u16* __restrict__ VTb,
    float* __restrict__ Hb)
{
    constexpr int NKC  = K / 16;
    constexpr int NNT  = MOUT / 32;
    constexpr int ROWB = K / 8;
    constexpr int NB   = 32 * ROWB;

    __shared__ u16 xs[32 * K];

    const int tid = threadIdx.x, wid = tid >> 6, lane = tid & 63;
    const int q = lane & 31, gp = lane >> 5;
    const int m0 = blockIdx.x * 32;

    for (int i = tid; i < NB; i += 256) {
        int row = i / ROWB, blk = i % ROWB;
        GLDS(&Xb[(size_t)(m0 + row) * K + 8 * (blk ^ (row & 7))], &xs[i * 8]);
    }
    __syncthreads();

    f32x16 acc[NNT];
#pragma unroll
    for (int nt = 0; nt < NNT; nt++) acc[nt] = f32x16{};

    const u16* wbase = WT + (size_t)wid * MOUT * K;

#pragma unroll 4
    for (int c = 0; c < NKC; c++) {
        bf16x8 af = *(const bf16x8*)&xs[q * K + 8 * ((2 * c + gp) ^ (q & 7))];
#pragma unroll
        for (int nt = 0; nt < NNT; nt++) {
            bf16x8 bf = *(const bf16x8*)&wbase[(size_t)(nt * 32 + q) * K + 16 * c + 8 * gp];
            acc[nt] = __builtin_amdgcn_mfma_f32_32x32x16_bf16(af, bf, acc[nt], 0, 0, 0);
        }
    }

    if (wid == 0) {
#pragma unroll
        for (int nt = 0; nt < NNT; nt++) {
            float bb = bq[nt * 32 + q] * LOG2E;
#pragma unroll
            for (int r = 0; r < 16; r++) {
                int grow = m0 + (r & 3) + 8 * (r >> 2) + 4 * gp;
                Qb[(size_t)grow * MOUT + nt * 32 + q] = (u16)f2bf(acc[nt][r] + bb);
            }
        }
    } else if (wid == 1) {
#pragma unroll
        for (int nt = 0; nt < NNT; nt++) {
            float bb = bk[nt * 32 + q];
#pragma unroll
            for (int r = 0; r < 16; r++) {
                int grow = m0 + (r & 3) + 8 * (r >> 2) + 4 * gp;
                Kb[(size_t)grow * MOUT + nt * 32 + q] = (u16)f2bf(acc[nt][r] + bb);
            }
        }
    } else if (wid == 2) {
#pragma unroll
        for (int nt = 0; nt < NNT; nt++) {
            float bb = bv[nt * 32 + q];
            u16* vrow = &VTb[(size_t)(nt * 32 + q) * NPAD];
#pragma unroll
            for (int g = 0; g < 4; g++) {
                ushort4 s;
                s.x = (u16)f2bf(acc[nt][4 * g + 0] + bb);
                s.y = (u16)f2bf(acc[nt][4 * g + 1] + bb);
                s.z = (u16)f2bf(acc[nt][4 * g + 2] + bb);
                s.w = (u16)f2bf(acc[nt][4 * g + 3] + bb);
                *(ushort4*)&vrow[m0 + 8 * g + 4 * gp] = s;
            }
        }
    } else {
#pragma unroll
        for (int nt = 0; nt < NNT; nt++) {
#pragma unroll
            for (int r = 0; r < 16; r++) {
                int grow = m0 + (r & 3) + 8 * (r >> 2) + 4 * gp;
                if (grow < N_NODES)
                    Hb[(size_t)grow * MOUT + nt * 32 + q] = acc[nt][r];
            }
        }
    }
}

// ---------------------------------------------------------------------------
// MFMA GEMM for Ws layers (verified R8).
// ---------------------------------------------------------------------------
template<int K, int MOUT, int OM, int NW>
__global__ __launch_bounds__(NW * 64) void s_gemm_mfma(
    const u16* __restrict__ Ab, const u16* __restrict__ WT,
    const float* __restrict__ bias, void* __restrict__ Cv)
{
    constexpr int NKC  = K / 16;
    constexpr int ROWB = K / 8;
    constexpr int NB   = 32 * ROWB;

    __shared__ u16 xs[32 * K];

    const int tid = threadIdx.x, wid = tid >> 6, lane = tid & 63;
    const int q = lane & 31, gp = lane >> 5;
    const int m0 = blockIdx.x * 32;

    for (int i = tid; i < NB; i += NW * 64) {
        int row = i / ROWB, blk = i % ROWB;
        GLDS(&Ab[(size_t)(m0 + row) * K + 8 * (blk ^ (row & 7))], &xs[i * 8]);
    }
    __syncthreads();

    f32x16 acc = f32x16{};
    const u16* wbase = WT + (size_t)(wid * 32) * K;

#pragma unroll 4
    for (int c = 0; c < NKC; c++) {
        bf16x8 af = *(const bf16x8*)&xs[q * K + 8 * ((2 * c + gp) ^ (q & 7))];
        bf16x8 bf = *(const bf16x8*)&wbase[(size_t)q * K + 16 * c + 8 * gp];
        acc = __builtin_amdgcn_mfma_f32_32x32x16_bf16(af, bf, acc, 0, 0, 0);
    }

    float bb = bias[wid * 32 + q];
#pragma unroll
    for (int r = 0; r < 16; r++) {
        int grow = m0 + (r & 3) + 8 * (r >> 2) + 4 * gp;
        float v = fmaxf(acc[r] + bb, 0.f);
        if (OM == 0) {
            if (grow < N_NODES) ((float*)Cv)[(size_t)grow * MOUT + wid * 32 + q] = v;
        } else {
            ((u16*)Cv)[(size_t)grow * MOUT + wid * 32 + q] = (u16)f2bf(v);
        }
    }
}

// ---------------------------------------------------------------------------
// Flash-decoding MFMA attention with FIXED-REFERENCE softmax (m0 = 0, exp2
// domain). 4 waves/block share the double-buffered K/V LDS tile; S splits.
// (verified R9/R12 @ 248 us; this round adds only s_setprio around MFMA)
// ---------------------------------------------------------------------------
template<int D, int S>
__global__ __launch_bounds__(256) void attn_split(
    const u16* __restrict__ Qg, const u16* __restrict__ Kg,
    const u16* __restrict__ VTg, u16* __restrict__ PO, float* __restrict__ PL)
{
    constexpr int NCH   = D / 16;
    constexpr int NDT   = D / 32;
    constexpr int KROWB = D / 8;
    constexpr int KI    = (32 * D) / 512;
    constexpr int VI    = (D * 32) / 512;
    constexpr int NKS   = KI / 4;
    constexpr int NVS   = VI / 4;
    constexpr int NT    = (N_NODES + 31) / 32;   // 251
    constexpr int CHUNK = (NT + S - 1) / S;

    __shared__ u16 kb[2][32 * D];
    __shared__ u16 vb[2][D * 32];

    const int tid  = threadIdx.x;
    const int wid  = tid >> 6;
    const int lane = tid & 63;
    const int q    = lane & 31;
    const int gp   = lane >> 5;
    const int sp   = blockIdx.x;
    const int q0   = blockIdx.y * 128 + wid * 32;

    bf16x8 qf[NCH];
    {
        int row = min(q0 + q, N_NODES - 1);
        const u16* qr = &Qg[(size_t)row * D + 8 * gp];
#pragma unroll
        for (int c = 0; c < NCH; c++)
            qf[c] = *(const bf16x8*)&qr[16 * c];
    }

    const int arow = (q & ~12) | ((q & 4) << 1) | ((q & 8) >> 1);
    const int hK   = (arow & 3) | (((arow >> 3) & 1) << 2);

    f32x16 acc[NDT];
#pragma unroll
    for (int i = 0; i < NDT; i++) acc[i] = f32x16{};
    float l = 0.f;

    const int t0 = sp * CHUNK;
    const int t1 = min(t0 + CHUNK, NT);

    const u16* kp[NKS]; int kdo[NKS];
#pragma unroll
    for (int s = 0; s < NKS; s++) {
        int i   = wid + 4 * s;
        int B   = i * 64 + lane;
        int row = B / KROWB;
        int bk  = B & (KROWB - 1);
        int h   = (row & 3) | (((row >> 3) & 1) << 2);
        kp[s]  = &Kg[(size_t)(t0 * 32 + row) * D + 8 * (bk ^ h)];
        kdo[s] = i * 512;
    }
    const u16* vp[NVS]; int vdo[NVS];
#pragma unroll
    for (int s = 0; s < NVS; s++) {
        int i  = wid + 4 * s;
        int B  = i * 64 + lane;
        int d  = B >> 2;
        int bv = B & 3;
        vp[s]  = &VTg[(size_t)d * NPAD + t0 * 32 + 8 * (bv ^ (d & 3))];
        vdo[s] = i * 512;
    }

    auto stage = [&](int buf) {
        u16* kdst = &kb[buf][0];
        u16* vdst = &vb[buf][0];
#pragma unroll
        for (int s = 0; s < NKS; s++) GLDS(kp[s], &kdst[kdo[s]]);
#pragma unroll
        for (int s = 0; s < NVS; s++) GLDS(vp[s], &vdst[vdo[s]]);
    };
    auto advance = [&]() {
#pragma unroll
        for (int s = 0; s < NKS; s++) kp[s] += 32 * D;
#pragma unroll
        for (int s = 0; s < NVS; s++) vp[s] += 32;
    };

    stage(0);
    advance();
    __syncthreads();

    for (int t = t0; t < t1; t++) {
        const int b = (t - t0) & 1;
        if (t + 1 < t1) { stage(b ^ 1); advance(); }

        const u16* kbt = &kb[b][0];
        const u16* vbt = &vb[b][0];
        const int j0 = t * 32;

        f32x16 st = f32x16{};
        __builtin_amdgcn_s_setprio(1);
#pragma unroll
        for (int c = 0; c < NCH; c++) {
            bf16x8 af = *(const bf16x8*)&kbt[arow * D + 8 * ((2 * c + gp) ^ hK)];
            st = __builtin_amdgcn_mfma_f32_32x32x16_bf16(af, qf[c], st, 0, 0, 0);
        }
        __builtin_amdgcn_s_setprio(0);

        if (j0 + 32 > N_NODES) {
#pragma unroll
            for (int r = 0; r < 16; r++) {
                int kl = (r & 3) + (((r >> 2) & 1) << 2) + ((r >> 3) << 4) + 8 * gp;
                if (j0 + kl >= N_NODES) st[r] = -INFINITY;
            }
        }

        float pv[16]; float ps = 0.f;
#pragma unroll
        for (int r = 0; r < 16; r++) { pv[r] = exp2f(st[r]); ps += pv[r]; }
        ps += __shfl_xor(ps, 32);
        l += ps;

        int4 w0 = { pk2(pv[0],  pv[1]),  pk2(pv[2],  pv[3]),
                    pk2(pv[4],  pv[5]),  pk2(pv[6],  pv[7]) };
        int4 w1 = { pk2(pv[8],  pv[9]),  pk2(pv[10], pv[11]),
                    pk2(pv[12], pv[13]), pk2(pv[14], pv[15]) };
        bf16x8 bp0 = __builtin_bit_cast(bf16x8, w0);
        bf16x8 bp1 = __builtin_bit_cast(bf16x8, w1);

        __builtin_amdgcn_s_setprio(1);
#pragma unroll
        for (int dt = 0; dt < NDT; dt++) {
            const int d = 32 * dt + q;
            bf16x8 vf0 = *(const bf16x8*)&vbt[d * 32 + 8 * ((gp)     ^ (d & 3))];
            acc[dt] = __builtin_amdgcn_mfma_f32_32x32x16_bf16(vf0, bp0, acc[dt], 0, 0, 0);
            bf16x8 vf1 = *(const bf16x8*)&vbt[d * 32 + 8 * ((2 + gp) ^ (d & 3))];
            acc[dt] = __builtin_amdgcn_mfma_f32_32x32x16_bf16(vf1, bp1, acc[dt], 0, 0, 0);
        }
        __builtin_amdgcn_s_setprio(0);
        __syncthreads();
    }

    const int qrl = q0 + q;
    if (gp == 0) PL[(size_t)sp * NQTOT + qrl] = l;
    u16* po = &PO[((size_t)sp * NQTOT + qrl) * D];
#pragma unroll
    for (int dt = 0; dt < NDT; dt++)
#pragma unroll
        for (int k = 0; k < 4; k++) {
            int2 w = { pk2(acc[dt][4 * k + 0], acc[dt][4 * k + 1]),
                       pk2(acc[dt][4 * k + 2], acc[dt][4 * k + 3]) };
            *(int2*)&po[32 * dt + 8 * k + 4 * gp] = w;
        }
}

// ---------------------------------------------------------------------------
// Fused merge + gather (fixed-reference: plain sums). Emits relu'd bf16 into
// AR[row][2C] = [G | R].
// ---------------------------------------------------------------------------
template<int C, int S>
__global__ __launch_bounds__(256) void merge_gather(
    const u16* __restrict__ PO, const float* __restrict__ PL,
    const float* __restrict__ h, const int* __restrict__ rowptr,
    const int2* __restrict__ csr, const float* __restrict__ dinv,
    const float* __restrict__ bias, u16* __restrict__ AR)
{
    constexpr int MB  = (NPAD * (C / 4)) / 256;   // merge blocks (exact)
    constexpr int LPN = C / 4;
    constexpr int NPB = 256 / LPN;

    const int tid = threadIdx.x;
    if ((int)blockIdx.x < MB) {
        int t  = blockIdx.x * 256 + tid;
        int qr = t / (C / 4);
        int d4 = (t % (C / 4)) * 4;

        float L = 0.f;
#pragma unroll
        for (int s = 0; s < S; s++) L += PL[(size_t)s * NQTOT + qr];
        float4 o = make_float4(0.f, 0.f, 0.f, 0.f);
#pragma unroll
        for (int s = 0; s < S; s++) {
            ushort4 p = *(const ushort4*)&PO[((size_t)s * NQTOT + qr) * C + d4];
            o.x += bf2f(p.x); o.y += bf2f(p.y);
            o.z += bf2f(p.z); o.w += bf2f(p.w);
        }
        float inv = 1.f / L;
        int2 w = { pk2(fmaxf(o.x * inv, 0.f), fmaxf(o.y * inv, 0.f)),
                   pk2(fmaxf(o.z * inv, 0.f), fmaxf(o.w * inv, 0.f)) };
        *(int2*)&AR[(size_t)qr * (2 * C) + C + d4] = w;
    } else {
        const int node = (blockIdx.x - MB) * NPB + tid / LPN;
        const int c4   = (tid % LPN) * 4;
        if (node >= N_NODES) return;
        const int r0 = rowptr[node], r1 = rowptr[node + 1];
        float4 acc = make_float4(0.f, 0.f, 0.f, 0.f);
        for (int j = r0; j < r1; j++) {
            int2 pk = csr[j];
            float nr = __int_as_float(pk.y);
            const float4 hv = *(const float4*)&h[(size_t)pk.x * C + c4];
            acc.x += hv.x * nr; acc.y += hv.y * nr;
            acc.z += hv.z * nr; acc.w += hv.w * nr;
        }
        float di = dinv[node];
        float sl = di * di;
        const float4 hs = *(const float4*)&h[(size_t)node * C + c4];
        const float4 bv = *(const float4*)&bias[c4];
        acc.x += hs.x * sl + bv.x; acc.y += hs.y * sl + bv.y;
        acc.z += hs.z * sl + bv.z; acc.w += hs.w * sl + bv.w;
        int2 w = { pk2(fmaxf(acc.x, 0.f), fmaxf(acc.y, 0.f)),
                   pk2(fmaxf(acc.z, 0.f), fmaxf(acc.w, 0.f)) };
        *(int2*)&AR[(size_t)node * (2 * C) + c4] = w;
    }
}

// ---------------------------------------------------------------------------
// GCN prep (CSR): prefix + dinv fused; cursor-atomic fill
// ---------------------------------------------------------------------------
__global__ __launch_bounds__(256) void prefix_rowptr(
    const int* __restrict__ degi, int* __restrict__ rowptr,
    int* __restrict__ cursor, float* __restrict__ dinv)
{
    __shared__ int sums[256];
    const int t = threadIdx.x;
    const int base = t * 32;
    int local[32];
    int s = 0;
#pragma unroll
    for (int i = 0; i < 32; i++) {
        int idx = base + i;
        local[i] = s;
        s += (idx < N_NODES) ? degi[idx] : 0;
    }
    sums[t] = s;
    __syncthreads();
    for (int o = 1; o < 256; o <<= 1) {
        int v = (t >= o) ? sums[t - o] : 0;
        __syncthreads();
        sums[t] += v;
        __syncthreads();
    }
    const int pre = (t == 0) ? 0 : sums[t - 1];
#pragma unroll
    for (int i = 0; i < 32; i++) {
        int idx = base + i;
        if (idx <= N_NODES) {
            int v = pre + local[i];
            rowptr[idx] = v;
            if (idx < N_NODES) cursor[idx] = v;
        }
    }
    for (int i = t; i < N_NODES; i += 256)
        dinv[i] = rsqrtf((float)degi[i] + 1.f);   // +1 self loop
}

__global__ void csr_fill(const int* __restrict__ ei, const float* __restrict__ dinv,
                         int* __restrict__ cursor, int2* __restrict__ csr)
{
    int e = blockIdx.x * blockDim.x + threadIdx.x;
    if (e >= E_EDGES) return;
    int s = ei[e], d = ei[E_EDGES + e];
    int pos = atomicAdd(&cursor[d], 1);
    int2 pk;
    pk.x = s;
    pk.y = __float_as_int(dinv[s] * dinv[d]);
    csr[pos] = pk;
}

// ---------------------------------------------------------------------------
// Head
// ---------------------------------------------------------------------------
// blocks 0..399: conv over bf rows; blocks 400..463: MIDAVG column means
__global__ __launch_bounds__(256) void conv_wv(
    const float* __restrict__ S2, const float* __restrict__ Wconv,
    const float* __restrict__ bconv, float* __restrict__ wvp,
    float* __restrict__ midavg)
{
    const int b = blockIdx.x, tid = threadIdx.x;
    if (b < 400) {
        __shared__ float wt[16 * 64];
        for (int idx = tid; idx < 1024; idx += 256) {
            int o = idx >> 8, rem = idx & 255, i = rem >> 2, k = rem & 3;
            wt[(k * 4 + o) * 64 + i] = Wconv[idx];
        }
        __syncthreads();

        const int wid = tid >> 6, d = tid & 63;
        const int t = b * 4 + wid;
        const float* base = S2 + (size_t)(1601 + 4 * t) * 64;
        const float v0 = base[d], v1 = base[64 + d], v2 = base[128 + d], v3 = base[192 + d];

        float p[4];
#pragma unroll
        for (int o = 0; o < 4; o++)
            p[o] = v0 * wt[(0 * 4 + o) * 64 + d] + v1 * wt[(1 * 4 + o) * 64 + d]
                 + v2 * wt[(2 * 4 + o) * 64 + d] + v3 * wt[(3 * 4 + o) * 64 + d];

#pragma unroll
        for (int o = 0; o < 4; o++)
#pragma unroll
            for (int off = 1; off < 64; off <<= 1) p[o] += __shfl_xor(p[o], off);

        if (d == 0) {
#pragma unroll
            for (int o = 0; o < 4; o++) wvp[4 * t + o] = p[o] + bconv[o];
        }
    } else {
        const int c = b - 400;
        float s = 0.f;
        for (int r = tid; r < 1600; r += 256) s += S2[64 + (size_t)r * 64 + c];
        for (int o = 32; o > 0; o >>= 1) s += __shfl_xor(s, o);
        __shared__ float sm[4];
        if ((tid & 63) == 0) sm[tid >> 6] = s;
        __syncthreads();
        if (tid == 0)
            midavg[c] = (sm[0] + sm[1] + sm[2] + sm[3]) * (1.f / 1600.f);
    }
}

// fused: blocks 0..6 -> wv_norm (gmax recomputed in-block), 7..106 -> copy_mid
__global__ __launch_bounds__(256) void wv_copy(
    const float* __restrict__ wvp, const float* __restrict__ S2,
    float* __restrict__ wv, float* __restrict__ out)
{
    const int b = blockIdx.x, tid = threadIdx.x;
    if (b < 7) {
        float mv = -INFINITY;
        for (int i = tid; i < 6400; i += 256) mv = fmaxf(mv, wvp[i]);
#pragma unroll
        for (int o = 32; o > 0; o >>= 1) mv = fmaxf(mv, __shfl_xor(mv, o));
        __shared__ float sm[4];
        if ((tid & 63) == 0) sm[tid >> 6] = mv;
        __syncthreads();
        const float g = fmaxf(fmaxf(sm[0], sm[1]), fmaxf(sm[2], sm[3]));
        int t = b * 256 + tid;
        if (t < 1600) {
            float v0 = wvp[4 * t + 0] / g, v1 = wvp[4 * t + 1] / g;
            float v2 = wvp[4 * t + 2] / g, v3 = wvp[4 * t + 3] / g;
            float s = fabsf(v0) + fabsf(v1) + fabsf(v2) + fabsf(v3);
            float r0 = v0 / s, r1 = v1 / s, r2 = v2 / s, r3 = v3 / s;
            wv[4 * t + 0] = r0; wv[4 * t + 1] = r1;
            wv[4 * t + 2] = r2; wv[4 * t + 3] = r3;
            out[272 + 4 * t + 0] = r0; out[272 + 4 * t + 1] = r1;
            out[272 + 4 * t + 2] = r2; out[272 + 4 * t + 3] = r3;
        }
    } else {
        int i = (b - 7) * 256 + tid;
        if (i < 25600) ((float4*)(out + 6672))[i] = ((const float4*)(S2 + 64))[i];
    }
}

// tree_bottom + BOTW column-sum accumulation (unscaled; scaled in head_kernel)
__global__ __launch_bounds__(256) void tree_bottom_kernel(
    const float* __restrict__ S2, const float* __restrict__ wv,
    float* __restrict__ out, float* __restrict__ botw_raw)
{
    __shared__ float red[256];
    int t = blockIdx.x * 256 + threadIdx.x;   // grid 400*256 = 1600*64 exactly
    int mg = t >> 6, c = t & 63;
    const float* base = S2 + (size_t)(1601 + 4 * mg) * 64 + c;
    float v = wv[4 * mg + 0] * base[0]   + wv[4 * mg + 1] * base[64]
            + wv[4 * mg + 2] * base[128] + wv[4 * mg + 3] * base[192];
    out[t] = v;
    red[threadIdx.x] = v;
    __syncthreads();
    if (threadIdx.x < 64) {
        float s = red[threadIdx.x] + red[threadIdx.x + 64]
                + red[threadIdx.x + 128] + red[threadIdx.x + 192];
        atomicAdd(&botw_raw[threadIdx.x], s);
    }
}

__global__ void head_kernel(const float* __restrict__ S2,
                            const float* __restrict__ midavg, const float* __restrict__ botw_raw,
                            const float* __restrict__ Wtw,  const float* __restrict__ btw,
                            const float* __restrict__ Wmid, const float* __restrict__ bmid,
                            const float* __restrict__ Wbot, const float* __restrict__ bbot,
                            const float* __restrict__ Wfc1, const float* __restrict__ bfc1,
                            const float* __restrict__ Wfc2, const float* __restrict__ bfc2,
                            float* __restrict__ out)
{
    __shared__ float cat[192];
    __shared__ float gf[64];
    int t = threadIdx.x;   // 64 threads
    float twv = S2[t];
    float bw  = botw_raw[t] * (1.f / 1600.f);
    cat[t]       = twv;
    cat[64 + t]  = midavg[t];
    cat[128 + t] = bw;
    out[80 + t]  = twv;
    out[144 + t] = midavg[t];
    out[208 + t] = bw;
    __syncthreads();
    float acc = bfc1[t];
    for (int k = 0; k < 192; k++) acc += cat[k] * Wfc1[k * 64 + t];
    gf[t] = acc;
    out[16 + t] = acc;
    __syncthreads();
    if (t < 4) {
        float og = bfc2[t], ot = btw[t], om = bmid[t], ob = bbot[t];
        for (int c = 0; c < 64; c++) {
            og += fmaxf(gf[c], 0.f) * Wfc2[c * 4 + t];
            ot += cat[c]        * Wtw[c * 4 + t];
            om += cat[64 + c]   * Wmid[c * 4 + t];
            ob += cat[128 + c]  * Wbot[c * 4 + t];
        }
        out[0 + t] = og; out[4 + t] = ot; out[8 + t] = om; out[12 + t] = ob;
    }
}

// ---------------------------------------------------------------------------
extern "C" void kernel_launch(void* const* d_in, const int* in_sizes, int n_in,
                              void* d_out, int out_size, void* d_ws, size_t ws_size,
                              hipStream_t stream)
{
    (void)in_sizes; (void)n_in; (void)out_size; (void)ws_size;
    const float* x    = (const float*)d_in[0];
    const int*   ei   = (const int*)d_in[1];
    const float* Wq1  = (const float*)d_in[2];  const float* bq1 = (const float*)d_in[3];
    const float* Wk1  = (const float*)d_in[4];  const float* bk1 = (const float*)d_in[5];
    const float* Wv1  = (const float*)d_in[6];  const float* bv1 = (const float*)d_in[7];
    const float* Wq2  = (const float*)d_in[8];  const float* bq2 = (const float*)d_in[9];
    const float* Wk2  = (const float*)d_in[10]; const float* bk2 = (const float*)d_in[11];
    const float* Wv2  = (const float*)d_in[12]; const float* bv2 = (const float*)d_in[13];
    const float* Wg1  = (const float*)d_in[14]; const float* bg1 = (const float*)d_in[15];
    const float* Wg2  = (const float*)d_in[16]; const float* bg2 = (const float*)d_in[17];
    const float* Ws1  = (const float*)d_in[18]; const float* bs1 = (const float*)d_in[19];
    const float* Ws2  = (const float*)d_in[20]; const float* bs2 = (const float*)d_in[21];
    const float* Wfc1 = (const float*)d_in[22]; const float* bfc1= (const float*)d_in[23];
    const float* Wfc2 = (const float*)d_in[24]; const float* bfc2= (const float*)d_in[25];
    const float* Wtw  = (const float*)d_in[26]; const float* btw = (const float*)d_in[27];
    const float* Wmid = (const float*)d_in[28]; const float* bmid= (const float*)d_in[29];
    const float* Wbot = (const float*)d_in[30]; const float* bbot= (const float*)d_in[31];
    const float* Wconv= (const float*)d_in[32]; const float* bconv=(const float*)d_in[33];

    float* out = (float*)d_out;
    float* ws  = (float*)d_ws;

    const size_t N128 = (size_t)N_NODES * 128;
    const size_t BF128 = (size_t)NPAD * 128 / 2;   // bf16 [NPAD][128] in float units

    size_t off = 0;
    auto alloc = [&](size_t n) { float* p = ws + off; off += (n + 15) & ~size_t(15); return p; };
    float* QB1  = alloc(BF128);               // bf16 [NPAD][128]
    float* KB1  = alloc(BF128);
    float* VTB1 = alloc(BF128);               // bf16 [128][NPAD]
    float* XB   = alloc((size_t)NPAD * 256);  // bf16 [NPAD][512]
    float* WT1  = alloc(4 * 128 * 512 / 2);   // bf16 [4][128][512]
    float* WT2  = alloc(4 * 64 * 128 / 2);    // bf16 [4][64][128]
    float* WST1 = alloc(128 * 256 / 2);       // bf16 [128][256]
    float* WST2 = alloc(64 * 128 / 2);        // bf16 [64][128]
    float* AR1  = alloc((size_t)NPAD * 128);  // bf16 [NPAD][256] = [G|R]
    float* S1B  = alloc((size_t)NPAD * 64);   // bf16 [NPAD][128]
    float* H1   = alloc(N128);                // f32
    float* S2   = alloc(N128);                // f32 [N][64] (only N*64 used)
    float* DINV = alloc(N_NODES);
    int*   DEGI   = (int*)alloc(8008);
    int*   ROWPTR = (int*)alloc(8008);
    int*   CURSOR = (int*)alloc(8008);
    int2*  CSR    = (int2*)alloc(2 * (size_t)E_EDGES);
    float* PO   = alloc((size_t)SP1 * NQTOT * 128 / 2);  // bf16 partials (SP2*64 == SP1*128)
    float* PL   = alloc((size_t)SP2 * NQTOT);
    float* WVP  = alloc(6400);
    float* WV   = alloc(6400);
    float* MIDAVG = alloc(64);
    float* BOTW   = alloc(64);
    // layer-2 aliases over dead layer-1 buffers
    float* QB2  = QB1;
    float* KB2  = KB1;
    float* VTB2 = VTB1;
    float* H2   = H1;
    float* AR2  = AR1;

    // prep: degree count + x cast + all weight transposes (one kernel)
    hipMemsetAsync(DEGI, 0, N_NODES * sizeof(int), stream);
    hipMemsetAsync(BOTW, 0, 64 * sizeof(float), stream);
    prep_all<<<3945, 256, 0, stream>>>(
        x, ei, Wq1, Wk1, Wv1, Wg1, Wq2, Wk2, Wv2, Wg2, Ws1, Ws2,
        DEGI, (u16*)XB, (u16*)WT1, (u16*)WT2, (u16*)WST1, (u16*)WST2);
    prefix_rowptr<<<1, 256, 0, stream>>>(DEGI, ROWPTR, CURSOR, DINV);
    csr_fill<<<(E_EDGES + 255) / 256, 256, 0, stream>>>(ei, DINV, CURSOR, CSR);

    // ---- layer 1 ----
    proj4_mfma<512, 128><<<NPAD / 32, 256, 0, stream>>>(
        (const u16*)XB, (const u16*)WT1, bq1, bk1, bv1,
        (u16*)QB1, (u16*)KB1, (u16*)VTB1, H1);

    attn_split<128, SP1><<<dim3(SP1, 63), 256, 0, stream>>>(
        (const u16*)QB1, (const u16*)KB1, (const u16*)VTB1, (u16*)PO, PL);

    {
        int mb = (NPAD * 32) / 256, gb = (N_NODES * 32 + 255) / 256;
        merge_gather<128, SP1><<<mb + gb, 256, 0, stream>>>(
            (const u16*)PO, PL, H1, ROWPTR, CSR, DINV, bg1, (u16*)AR1);
    }

    s_gemm_mfma<256, 128, 1, 4><<<NPAD / 32, 256, 0, stream>>>(
        (const u16*)AR1, (const u16*)WST1, bs1, (u16*)S1B);

    // ---- layer 2 ----
    proj4_mfma<128, 64><<<NPAD / 32, 256, 0, stream>>>(
        (const u16*)S1B, (const u16*)WT2, bq2, bk2, bv2,
        (u16*)QB2, (u16*)KB2, (u16*)VTB2, H2);

    attn_split<64, SP2><<<dim3(SP2, 63), 256, 0, stream>>>(
        (const u16*)QB2, (const u16*)KB2, (const u16*)VTB2, (u16*)PO, PL);

    {
        int mb = (NPAD * 16) / 256, gb = (N_NODES * 16 + 255) / 256;
        merge_gather<64, SP2><<<mb + gb, 256, 0, stream>>>(
            (const u16*)PO, PL, H2, ROWPTR, CSR, DINV, bg2, (u16*)AR2);
    }

    s_gemm_mfma<128, 64, 0, 2><<<NPAD / 32, 128, 0, stream>>>(
        (const u16*)AR2, (const u16*)WST2, bs2, S2);

    // ---- head ----
    conv_wv<<<464, 256, 0, stream>>>(S2, Wconv, bconv, WVP, MIDAVG);
    wv_copy<<<107, 256, 0, stream>>>(WVP, S2, WV, out);
    tree_bottom_kernel<<<400, 256, 0, stream>>>(S2, WV, out + 109072, BOTW);
    head_kernel<<<1, 64, 0, stream>>>(S2, MIDAVG, BOTW, Wtw, btw, Wmid, bmid,
                                      Wbot, bbot, Wfc1, bfc1, Wfc2, bfc2, out);
}

// Round 14
// 246.940 us; speedup vs baseline: 1.0548x; 1.0548x over previous
//
#include <hip/hip_runtime.h>
#include <math.h>

#define N_NODES 8001
#define NPAD    8032      // 251*32, padded row count for attention operands
#define E_EDGES 160000
#define NQTOT   8064      // 63*128, query rows covered by attn grid
#define LOG2E   1.4426950408889634f
#define NSPLIT  16

typedef unsigned short u16;
typedef __attribute__((ext_vector_type(8)))  short bf16x8;
typedef __attribute__((ext_vector_type(16))) float f32x16;

__device__ __forceinline__ short f2bf(float f) {
    unsigned u = __builtin_bit_cast(unsigned, f);
    u = (u + 0x7FFFu + ((u >> 16) & 1u)) >> 16;   // RNE
    return (short)u;
}
__device__ __forceinline__ float bf2f(u16 x) {
    return __builtin_bit_cast(float, (unsigned)x << 16);
}
// pack 2 f32 -> u32 of 2 bf16 (lo=a, hi=b), single instruction
__device__ __forceinline__ int pk2(float a, float b) {
    int r;
    asm("v_cvt_pk_bf16_f32 %0, %1, %2" : "=v"(r) : "v"(a), "v"(b));
    return r;
}

#define GLDS(g, l) __builtin_amdgcn_global_load_lds( \
    (const __attribute__((address_space(1))) void*)(g), \
    (__attribute__((address_space(3))) void*)(l), 16, 0, 0)

// ---------------------------------------------------------------------------
// Fused prep: blocks [0,625) edge-degree count; [625,2633) x -> bf16 cast;
// [2633,3945) all weight transposes (Q-slices scaled by log2e).
// ---------------------------------------------------------------------------
__global__ __launch_bounds__(256) void prep_all(
    const float* __restrict__ x, const int* __restrict__ ei,
    const float* __restrict__ Wq1, const float* __restrict__ Wk1,
    const float* __restrict__ Wv1, const float* __restrict__ Wg1,
    const float* __restrict__ Wq2, const float* __restrict__ Wk2,
    const float* __restrict__ Wv2, const float* __restrict__ Wg2,
    const float* __restrict__ Ws1, const float* __restrict__ Ws2,
    int* __restrict__ degi, u16* __restrict__ XB,
    u16* __restrict__ WT1, u16* __restrict__ WT2,
    u16* __restrict__ WST1, u16* __restrict__ WST2)
{
    const int b = blockIdx.x, tid = threadIdx.x;
    if (b < 625) {
        int e = b * 256 + tid;
        if (e < E_EDGES) atomicAdd(&degi[ei[E_EDGES + e]], 1);
    } else if (b < 2633) {            // cast x (K=512): 8 elems/thread
        size_t t = (size_t)(b - 625) * 256 + tid;
        int row = (int)(t / 64), c8 = (int)(t % 64) * 8;
        int lrow = min(row, N_NODES - 1);
        const float4* p = (const float4*)&x[(size_t)lrow * 512 + c8];
        float4 u = p[0], v = p[1];
        int4 w = { pk2(u.x, u.y), pk2(u.z, u.w), pk2(v.x, v.y), pk2(v.z, v.w) };
        *(int4*)&XB[t * 8] = w;
    } else if (b < 3657) {            // WT1 [4][128][512]
        int t = (b - 2633) * 256 + tid;
        int p = t / (128 * 512), n = (t / 512) & 127, k = t % 512;
        const float* W = (p == 0) ? Wq1 : (p == 1) ? Wk1 : (p == 2) ? Wv1 : Wg1;
        float v = W[k * 128 + n];
        if (p == 0) v *= LOG2E;
        WT1[t] = (u16)f2bf(v);
    } else if (b < 3785) {            // WT2 [4][64][128]
        int t = (b - 3657) * 256 + tid;
        int p = t / (64 * 128), n = (t / 128) & 63, k = t & 127;
        const float* W = (p == 0) ? Wq2 : (p == 1) ? Wk2 : (p == 2) ? Wv2 : Wg2;
        float v = W[k * 64 + n];
        if (p == 0) v *= LOG2E;
        WT2[t] = (u16)f2bf(v);
    } else if (b < 3913) {            // WST1 [128][256]
        int t = (b - 3785) * 256 + tid;
        int n = t >> 8, k = t & 255;
        WST1[t] = (u16)f2bf(Ws1[k * 128 + n]);
    } else {                          // WST2 [64][128]
        int t = (b - 3913) * 256 + tid;
        int n = t >> 7, k = t & 127;
        WST2[t] = (u16)f2bf(Ws2[k * 64 + n]);
    }
}

// ---------------------------------------------------------------------------
// MFMA fused 4-way projection (verified R7).
// ---------------------------------------------------------------------------
template<int K, int MOUT>
__global__ __launch_bounds__(256) void proj4_mfma(
    const u16* __restrict__ Xb, const u16* __restrict__ WT,
    const float* __restrict__ bq, const float* __restrict__ bk,
    const float* __restrict__ bv,
    u16* __restrict__ Qb, u16* __restrict__ Kb, u16* __restrict__ VTb,
    float* __restrict__ Hb)
{
    constexpr int NKC  = K / 16;
    constexpr int NNT  = MOUT / 32;
    constexpr int ROWB = K / 8;
    constexpr int NB   = 32 * ROWB;

    __shared__ u16 xs[32 * K];

    const int tid = threadIdx.x, wid = tid >> 6, lane = tid & 63;
    const int q = lane & 31, gp = lane >> 5;
    const int m0 = blockIdx.x * 32;

    for (int i = tid; i < NB; i += 256) {
        int row = i / ROWB, blk = i % ROWB;
        GLDS(&Xb[(size_t)(m0 + row) * K + 8 * (blk ^ (row & 7))], &xs[i * 8]);
    }
    __syncthreads();

    f32x16 acc[NNT];
#pragma unroll
    for (int nt = 0; nt < NNT; nt++) acc[nt] = f32x16{};

    const u16* wbase = WT + (size_t)wid * MOUT * K;

#pragma unroll 4
    for (int c = 0; c < NKC; c++) {
        bf16x8 af = *(const bf16x8*)&xs[q * K + 8 * ((2 * c + gp) ^ (q & 7))];
#pragma unroll
        for (int nt = 0; nt < NNT; nt++) {
            bf16x8 bf = *(const bf16x8*)&wbase[(size_t)(nt * 32 + q) * K + 16 * c + 8 * gp];
            acc[nt] = __builtin_amdgcn_mfma_f32_32x32x16_bf16(af, bf, acc[nt], 0, 0, 0);
        }
    }

    if (wid == 0) {
#pragma unroll
        for (int nt = 0; nt < NNT; nt++) {
            float bb = bq[nt * 32 + q] * LOG2E;
#pragma unroll
            for (int r = 0; r < 16; r++) {
                int grow = m0 + (r & 3) + 8 * (r >> 2) + 4 * gp;
                Qb[(size_t)grow * MOUT + nt * 32 + q] = (u16)f2bf(acc[nt][r] + bb);
            }
        }
    } else if (wid == 1) {
#pragma unroll
        for (int nt = 0; nt < NNT; nt++) {
            float bb = bk[nt * 32 + q];
#pragma unroll
            for (int r = 0; r < 16; r++) {
                int grow = m0 + (r & 3) + 8 * (r >> 2) + 4 * gp;
                Kb[(size_t)grow * MOUT + nt * 32 + q] = (u16)f2bf(acc[nt][r] + bb);
            }
        }
    } else if (wid == 2) {
#pragma unroll
        for (int nt = 0; nt < NNT; nt++) {
            float bb = bv[nt * 32 + q];
            u16* vrow = &VTb[(size_t)(nt * 32 + q) * NPAD];
#pragma unroll
            for (int g = 0; g < 4; g++) {
                ushort4 s;
                s.x = (u16)f2bf(acc[nt][4 * g + 0] + bb);
                s.y = (u16)f2bf(acc[nt][4 * g + 1] + bb);
                s.z = (u16)f2bf(acc[nt][4 * g + 2] + bb);
                s.w = (u16)f2bf(acc[nt][4 * g + 3] + bb);
                *(ushort4*)&vrow[m0 + 8 * g + 4 * gp] = s;
            }
        }
    } else {
#pragma unroll
        for (int nt = 0; nt < NNT; nt++) {
#pragma unroll
            for (int r = 0; r < 16; r++) {
                int grow = m0 + (r & 3) + 8 * (r >> 2) + 4 * gp;
                if (grow < N_NODES)
                    Hb[(size_t)grow * MOUT + nt * 32 + q] = acc[nt][r];
            }
        }
    }
}

// ---------------------------------------------------------------------------
// MFMA GEMM for Ws layers (verified R8).
// ---------------------------------------------------------------------------
template<int K, int MOUT, int OM, int NW>
__global__ __launch_bounds__(NW * 64) void s_gemm_mfma(
    const u16* __restrict__ Ab, const u16* __restrict__ WT,
    const float* __restrict__ bias, void* __restrict__ Cv)
{
    constexpr int NKC  = K / 16;
    constexpr int ROWB = K / 8;
    constexpr int NB   = 32 * ROWB;

    __shared__ u16 xs[32 * K];

    const int tid = threadIdx.x, wid = tid >> 6, lane = tid & 63;
    const int q = lane & 31, gp = lane >> 5;
    const int m0 = blockIdx.x * 32;

    for (int i = tid; i < NB; i += NW * 64) {
        int row = i / ROWB, blk = i % ROWB;
        GLDS(&Ab[(size_t)(m0 + row) * K + 8 * (blk ^ (row & 7))], &xs[i * 8]);
    }
    __syncthreads();

    f32x16 acc = f32x16{};
    const u16* wbase = WT + (size_t)(wid * 32) * K;

#pragma unroll 4
    for (int c = 0; c < NKC; c++) {
        bf16x8 af = *(const bf16x8*)&xs[q * K + 8 * ((2 * c + gp) ^ (q & 7))];
        bf16x8 bf = *(const bf16x8*)&wbase[(size_t)q * K + 16 * c + 8 * gp];
        acc = __builtin_amdgcn_mfma_f32_32x32x16_bf16(af, bf, acc, 0, 0, 0);
    }

    float bb = bias[wid * 32 + q];
#pragma unroll
    for (int r = 0; r < 16; r++) {
        int grow = m0 + (r & 3) + 8 * (r >> 2) + 4 * gp;
        float v = fmaxf(acc[r] + bb, 0.f);
        if (OM == 0) {
            if (grow < N_NODES) ((float*)Cv)[(size_t)grow * MOUT + wid * 32 + q] = v;
        } else {
            ((u16*)Cv)[(size_t)grow * MOUT + wid * 32 + q] = (u16)f2bf(v);
        }
    }
}

// ---------------------------------------------------------------------------
// Flash-decoding MFMA attention with FIXED-REFERENCE softmax (m0 = 0, exp2
// domain): p = exp2(st), l = sum p. Powers-of-2 scaling is exact, so no max
// tracking / rescale / defer is needed, and merge is a plain sum.
// 4 waves/block share the double-buffered K/V LDS tile; S key-splits.
// (verified R9/R12 @ 248 us)
// ---------------------------------------------------------------------------
template<int D, int S>
__global__ __launch_bounds__(256) void attn_split(
    const u16* __restrict__ Qg, const u16* __restrict__ Kg,
    const u16* __restrict__ VTg, u16* __restrict__ PO, float* __restrict__ PL)
{
    constexpr int NCH   = D / 16;
    constexpr int NDT   = D / 32;
    constexpr int KROWB = D / 8;
    constexpr int KI    = (32 * D) / 512;
    constexpr int VI    = (D * 32) / 512;
    constexpr int NKS   = KI / 4;
    constexpr int NVS   = VI / 4;
    constexpr int NT    = (N_NODES + 31) / 32;   // 251
    constexpr int CHUNK = (NT + S - 1) / S;

    __shared__ u16 kb[2][32 * D];
    __shared__ u16 vb[2][D * 32];

    const int tid  = threadIdx.x;
    const int wid  = tid >> 6;
    const int lane = tid & 63;
    const int q    = lane & 31;
    const int gp   = lane >> 5;
    const int sp   = blockIdx.x;
    const int q0   = blockIdx.y * 128 + wid * 32;

    bf16x8 qf[NCH];
    {
        int row = min(q0 + q, N_NODES - 1);
        const u16* qr = &Qg[(size_t)row * D + 8 * gp];
#pragma unroll
        for (int c = 0; c < NCH; c++)
            qf[c] = *(const bf16x8*)&qr[16 * c];
    }

    const int arow = (q & ~12) | ((q & 4) << 1) | ((q & 8) >> 1);
    const int hK   = (arow & 3) | (((arow >> 3) & 1) << 2);

    f32x16 acc[NDT];
#pragma unroll
    for (int i = 0; i < NDT; i++) acc[i] = f32x16{};
    float l = 0.f;

    const int t0 = sp * CHUNK;
    const int t1 = min(t0 + CHUNK, NT);

    const u16* kp[NKS]; int kdo[NKS];
#pragma unroll
    for (int s = 0; s < NKS; s++) {
        int i   = wid + 4 * s;
        int B   = i * 64 + lane;
        int row = B / KROWB;
        int bk  = B & (KROWB - 1);
        int h   = (row & 3) | (((row >> 3) & 1) << 2);
        kp[s]  = &Kg[(size_t)(t0 * 32 + row) * D + 8 * (bk ^ h)];
        kdo[s] = i * 512;
    }
    const u16* vp[NVS]; int vdo[NVS];
#pragma unroll
    for (int s = 0; s < NVS; s++) {
        int i  = wid + 4 * s;
        int B  = i * 64 + lane;
        int d  = B >> 2;
        int bv = B & 3;
        vp[s]  = &VTg[(size_t)d * NPAD + t0 * 32 + 8 * (bv ^ (d & 3))];
        vdo[s] = i * 512;
    }

    auto stage = [&](int buf) {
        u16* kdst = &kb[buf][0];
        u16* vdst = &vb[buf][0];
#pragma unroll
        for (int s = 0; s < NKS; s++) GLDS(kp[s], &kdst[kdo[s]]);
#pragma unroll
        for (int s = 0; s < NVS; s++) GLDS(vp[s], &vdst[vdo[s]]);
    };
    auto advance = [&]() {
#pragma unroll
        for (int s = 0; s < NKS; s++) kp[s] += 32 * D;
#pragma unroll
        for (int s = 0; s < NVS; s++) vp[s] += 32;
    };

    stage(0);
    advance();
    __syncthreads();

    for (int t = t0; t < t1; t++) {
        const int b = (t - t0) & 1;
        if (t + 1 < t1) { stage(b ^ 1); advance(); }

        const u16* kbt = &kb[b][0];
        const u16* vbt = &vb[b][0];
        const int j0 = t * 32;

        f32x16 st = f32x16{};
#pragma unroll
        for (int c = 0; c < NCH; c++) {
            bf16x8 af = *(const bf16x8*)&kbt[arow * D + 8 * ((2 * c + gp) ^ hK)];
            st = __builtin_amdgcn_mfma_f32_32x32x16_bf16(af, qf[c], st, 0, 0, 0);
        }

        if (j0 + 32 > N_NODES) {
#pragma unroll
            for (int r = 0; r < 16; r++) {
                int kl = (r & 3) + (((r >> 2) & 1) << 2) + ((r >> 3) << 4) + 8 * gp;
                if (j0 + kl >= N_NODES) st[r] = -INFINITY;
            }
        }

        float pv[16]; float ps = 0.f;
#pragma unroll
        for (int r = 0; r < 16; r++) { pv[r] = exp2f(st[r]); ps += pv[r]; }
        ps += __shfl_xor(ps, 32);
        l += ps;

        int4 w0 = { pk2(pv[0],  pv[1]),  pk2(pv[2],  pv[3]),
                    pk2(pv[4],  pv[5]),  pk2(pv[6],  pv[7]) };
        int4 w1 = { pk2(pv[8],  pv[9]),  pk2(pv[10], pv[11]),
                    pk2(pv[12], pv[13]), pk2(pv[14], pv[15]) };
        bf16x8 bp0 = __builtin_bit_cast(bf16x8, w0);
        bf16x8 bp1 = __builtin_bit_cast(bf16x8, w1);

#pragma unroll
        for (int dt = 0; dt < NDT; dt++) {
            const int d = 32 * dt + q;
            bf16x8 vf0 = *(const bf16x8*)&vbt[d * 32 + 8 * ((gp)     ^ (d & 3))];
            acc[dt] = __builtin_amdgcn_mfma_f32_32x32x16_bf16(vf0, bp0, acc[dt], 0, 0, 0);
            bf16x8 vf1 = *(const bf16x8*)&vbt[d * 32 + 8 * ((2 + gp) ^ (d & 3))];
            acc[dt] = __builtin_amdgcn_mfma_f32_32x32x16_bf16(vf1, bp1, acc[dt], 0, 0, 0);
        }
        __syncthreads();
    }

    const int qrl = q0 + q;
    if (gp == 0) PL[(size_t)sp * NQTOT + qrl] = l;
    u16* po = &PO[((size_t)sp * NQTOT + qrl) * D];
#pragma unroll
    for (int dt = 0; dt < NDT; dt++)
#pragma unroll
        for (int k = 0; k < 4; k++) {
            int2 w = { pk2(acc[dt][4 * k + 0], acc[dt][4 * k + 1]),
                       pk2(acc[dt][4 * k + 2], acc[dt][4 * k + 3]) };
            *(int2*)&po[32 * dt + 8 * k + 4 * gp] = w;
        }
}

// ---------------------------------------------------------------------------
// Fused merge + gather (fixed-reference: plain sums). Emits relu'd bf16 into
// AR[row][2C] = [G | R].
// ---------------------------------------------------------------------------
template<int C, int S>
__global__ __launch_bounds__(256) void merge_gather(
    const u16* __restrict__ PO, const float* __restrict__ PL,
    const float* __restrict__ h, const int* __restrict__ rowptr,
    const int2* __restrict__ csr, const float* __restrict__ dinv,
    const float* __restrict__ bias, u16* __restrict__ AR)
{
    constexpr int MB  = (NPAD * (C / 4)) / 256;   // merge blocks (exact)
    constexpr int LPN = C / 4;
    constexpr int NPB = 256 / LPN;

    const int tid = threadIdx.x;
    if ((int)blockIdx.x < MB) {
        int t  = blockIdx.x * 256 + tid;
        int qr = t / (C / 4);
        int d4 = (t % (C / 4)) * 4;

        float L = 0.f;
#pragma unroll
        for (int s = 0; s < S; s++) L += PL[(size_t)s * NQTOT + qr];
        float4 o = make_float4(0.f, 0.f, 0.f, 0.f);
#pragma unroll
        for (int s = 0; s < S; s++) {
            ushort4 p = *(const ushort4*)&PO[((size_t)s * NQTOT + qr) * C + d4];
            o.x += bf2f(p.x); o.y += bf2f(p.y);
            o.z += bf2f(p.z); o.w += bf2f(p.w);
        }
        float inv = 1.f / L;
        int2 w = { pk2(fmaxf(o.x * inv, 0.f), fmaxf(o.y * inv, 0.f)),
                   pk2(fmaxf(o.z * inv, 0.f), fmaxf(o.w * inv, 0.f)) };
        *(int2*)&AR[(size_t)qr * (2 * C) + C + d4] = w;
    } else {
        const int node = (blockIdx.x - MB) * NPB + tid / LPN;
        const int c4   = (tid % LPN) * 4;
        if (node >= N_NODES) return;
        const int r0 = rowptr[node], r1 = rowptr[node + 1];
        float4 acc = make_float4(0.f, 0.f, 0.f, 0.f);
        for (int j = r0; j < r1; j++) {
            int2 pk = csr[j];
            float nr = __int_as_float(pk.y);
            const float4 hv = *(const float4*)&h[(size_t)pk.x * C + c4];
            acc.x += hv.x * nr; acc.y += hv.y * nr;
            acc.z += hv.z * nr; acc.w += hv.w * nr;
        }
        float di = dinv[node];
        float sl = di * di;
        const float4 hs = *(const float4*)&h[(size_t)node * C + c4];
        const float4 bv = *(const float4*)&bias[c4];
        acc.x += hs.x * sl + bv.x; acc.y += hs.y * sl + bv.y;
        acc.z += hs.z * sl + bv.z; acc.w += hs.w * sl + bv.w;
        int2 w = { pk2(fmaxf(acc.x, 0.f), fmaxf(acc.y, 0.f)),
                   pk2(fmaxf(acc.z, 0.f), fmaxf(acc.w, 0.f)) };
        *(int2*)&AR[(size_t)node * (2 * C) + c4] = w;
    }
}

// ---------------------------------------------------------------------------
// GCN prep (CSR): prefix + dinv fused; cursor-atomic fill
// ---------------------------------------------------------------------------
__global__ __launch_bounds__(256) void prefix_rowptr(
    const int* __restrict__ degi, int* __restrict__ rowptr,
    int* __restrict__ cursor, float* __restrict__ dinv)
{
    __shared__ int sums[256];
    const int t = threadIdx.x;
    const int base = t * 32;
    int local[32];
    int s = 0;
#pragma unroll
    for (int i = 0; i < 32; i++) {
        int idx = base + i;
        local[i] = s;
        s += (idx < N_NODES) ? degi[idx] : 0;
    }
    sums[t] = s;
    __syncthreads();
    for (int o = 1; o < 256; o <<= 1) {
        int v = (t >= o) ? sums[t - o] : 0;
        __syncthreads();
        sums[t] += v;
        __syncthreads();
    }
    const int pre = (t == 0) ? 0 : sums[t - 1];
#pragma unroll
    for (int i = 0; i < 32; i++) {
        int idx = base + i;
        if (idx <= N_NODES) {
            int v = pre + local[i];
            rowptr[idx] = v;
            if (idx < N_NODES) cursor[idx] = v;
        }
    }
    for (int i = t; i < N_NODES; i += 256)
        dinv[i] = rsqrtf((float)degi[i] + 1.f);   // +1 self loop
}

__global__ void csr_fill(const int* __restrict__ ei, const float* __restrict__ dinv,
                         int* __restrict__ cursor, int2* __restrict__ csr)
{
    int e = blockIdx.x * blockDim.x + threadIdx.x;
    if (e >= E_EDGES) return;
    int s = ei[e], d = ei[E_EDGES + e];
    int pos = atomicAdd(&cursor[d], 1);
    int2 pk;
    pk.x = s;
    pk.y = __float_as_int(dinv[s] * dinv[d]);
    csr[pos] = pk;
}

// ---------------------------------------------------------------------------
// Head
// ---------------------------------------------------------------------------
__global__ __launch_bounds__(256) void conv_wv(
    const float* __restrict__ S2, const float* __restrict__ Wconv,
    const float* __restrict__ bconv, float* __restrict__ wvp)
{
    __shared__ float wt[16 * 64];
    const int tid = threadIdx.x;
    for (int idx = tid; idx < 1024; idx += 256) {
        int o = idx >> 8, rem = idx & 255, i = rem >> 2, k = rem & 3;
        wt[(k * 4 + o) * 64 + i] = Wconv[idx];
    }
    __syncthreads();

    const int wid = tid >> 6, d = tid & 63;
    const int t = blockIdx.x * 4 + wid;
    const float* base = S2 + (size_t)(1601 + 4 * t) * 64;
    const float v0 = base[d], v1 = base[64 + d], v2 = base[128 + d], v3 = base[192 + d];

    float p[4];
#pragma unroll
    for (int o = 0; o < 4; o++)
        p[o] = v0 * wt[(0 * 4 + o) * 64 + d] + v1 * wt[(1 * 4 + o) * 64 + d]
             + v2 * wt[(2 * 4 + o) * 64 + d] + v3 * wt[(3 * 4 + o) * 64 + d];

#pragma unroll
    for (int o = 0; o < 4; o++)
#pragma unroll
        for (int off = 1; off < 64; off <<= 1) p[o] += __shfl_xor(p[o], off);

    if (d == 0) {
#pragma unroll
        for (int o = 0; o < 4; o++) wvp[4 * t + o] = p[o] + bconv[o];
    }
}

// fused: blocks 0..6 -> wv_norm (gmax recomputed in-block; max is
// order-independent so the value is bit-identical), blocks 7..106 -> copy_mid
__global__ __launch_bounds__(256) void wv_copy(
    const float* __restrict__ wvp, const float* __restrict__ S2,
    float* __restrict__ wv, float* __restrict__ out)
{
    const int b = blockIdx.x, tid = threadIdx.x;
    if (b < 7) {
        float mv = -INFINITY;
        for (int i = tid; i < 6400; i += 256) mv = fmaxf(mv, wvp[i]);
#pragma unroll
        for (int o = 32; o > 0; o >>= 1) mv = fmaxf(mv, __shfl_xor(mv, o));
        __shared__ float sm[4];
        if ((tid & 63) == 0) sm[tid >> 6] = mv;
        __syncthreads();
        const float g = fmaxf(fmaxf(sm[0], sm[1]), fmaxf(sm[2], sm[3]));
        int t = b * 256 + tid;
        if (t < 1600) {
            float v0 = wvp[4 * t + 0] / g, v1 = wvp[4 * t + 1] / g;
            float v2 = wvp[4 * t + 2] / g, v3 = wvp[4 * t + 3] / g;
            float s = fabsf(v0) + fabsf(v1) + fabsf(v2) + fabsf(v3);
            float r0 = v0 / s, r1 = v1 / s, r2 = v2 / s, r3 = v3 / s;
            wv[4 * t + 0] = r0; wv[4 * t + 1] = r1;
            wv[4 * t + 2] = r2; wv[4 * t + 3] = r3;
            out[272 + 4 * t + 0] = r0; out[272 + 4 * t + 1] = r1;
            out[272 + 4 * t + 2] = r2; out[272 + 4 * t + 3] = r3;
        }
    } else {
        int i = (b - 7) * 256 + tid;
        if (i < 25600) ((float4*)(out + 6672))[i] = ((const float4*)(S2 + 64))[i];
    }
}

__global__ void tree_bottom_kernel(const float* __restrict__ S2,
                                   const float* __restrict__ wv,
                                   float* __restrict__ out)
{
    int t = blockIdx.x * blockDim.x + threadIdx.x;
    if (t >= 1600 * 64) return;
    int mg = t >> 6, c = t & 63;
    const float* base = S2 + (size_t)(1601 + 4 * mg) * 64 + c;
    out[t] = wv[4 * mg + 0] * base[0]   + wv[4 * mg + 1] * base[64]
           + wv[4 * mg + 2] * base[128] + wv[4 * mg + 3] * base[192];
}

// fused column means: blocks 0..63 -> MIDAVG, blocks 64..127 -> BOTW
__global__ void col_mean2(const float* __restrict__ S2, const float* __restrict__ tb,
                          float* __restrict__ midavg, float* __restrict__ botw)
{
    const int b = blockIdx.x;
    const int c = b & 63;
    const float* in = (b < 64) ? (S2 + 64) : tb;
    float s = 0.f;
    for (int r = threadIdx.x; r < 1600; r += 256) s += in[(size_t)r * 64 + c];
    for (int o = 32; o > 0; o >>= 1) s += __shfl_xor(s, o);
    __shared__ float sm[4];
    if ((threadIdx.x & 63) == 0) sm[threadIdx.x >> 6] = s;
    __syncthreads();
    if (threadIdx.x == 0) {
        float v = (sm[0] + sm[1] + sm[2] + sm[3]) * (1.f / 1600.f);
        (b < 64 ? midavg : botw)[c] = v;
    }
}

__global__ void head_kernel(const float* __restrict__ S2,
                            const float* __restrict__ midavg, const float* __restrict__ botw,
                            const float* __restrict__ Wtw,  const float* __restrict__ btw,
                            const float* __restrict__ Wmid, const float* __restrict__ bmid,
                            const float* __restrict__ Wbot, const float* __restrict__ bbot,
                            const float* __restrict__ Wfc1, const float* __restrict__ bfc1,
                            const float* __restrict__ Wfc2, const float* __restrict__ bfc2,
                            float* __restrict__ out)
{
    __shared__ float cat[192];
    __shared__ float gf[64];
    int t = threadIdx.x;   // 64 threads
    float twv = S2[t];
    cat[t]       = twv;
    cat[64 + t]  = midavg[t];
    cat[128 + t] = botw[t];
    out[80 + t]  = twv;
    out[144 + t] = midavg[t];
    out[208 + t] = botw[t];
    __syncthreads();
    float acc = bfc1[t];
    for (int k = 0; k < 192; k++) acc += cat[k] * Wfc1[k * 64 + t];
    gf[t] = acc;
    out[16 + t] = acc;
    __syncthreads();
    if (t < 4) {
        float og = bfc2[t], ot = btw[t], om = bmid[t], ob = bbot[t];
        for (int c = 0; c < 64; c++) {
            og += fmaxf(gf[c], 0.f) * Wfc2[c * 4 + t];
            ot += cat[c]        * Wtw[c * 4 + t];
            om += cat[64 + c]   * Wmid[c * 4 + t];
            ob += cat[128 + c]  * Wbot[c * 4 + t];
        }
        out[0 + t] = og; out[4 + t] = ot; out[8 + t] = om; out[12 + t] = ob;
    }
}

// ---------------------------------------------------------------------------
extern "C" void kernel_launch(void* const* d_in, const int* in_sizes, int n_in,
                              void* d_out, int out_size, void* d_ws, size_t ws_size,
                              hipStream_t stream)
{
    (void)in_sizes; (void)n_in; (void)out_size; (void)ws_size;
    const float* x    = (const float*)d_in[0];
    const int*   ei   = (const int*)d_in[1];
    const float* Wq1  = (const float*)d_in[2];  const float* bq1 = (const float*)d_in[3];
    const float* Wk1  = (const float*)d_in[4];  const float* bk1 = (const float*)d_in[5];
    const float* Wv1  = (const float*)d_in[6];  const float* bv1 = (const float*)d_in[7];
    const float* Wq2  = (const float*)d_in[8];  const float* bq2 = (const float*)d_in[9];
    const float* Wk2  = (const float*)d_in[10]; const float* bk2 = (const float*)d_in[11];
    const float* Wv2  = (const float*)d_in[12]; const float* bv2 = (const float*)d_in[13];
    const float* Wg1  = (const float*)d_in[14]; const float* bg1 = (const float*)d_in[15];
    const float* Wg2  = (const float*)d_in[16]; const float* bg2 = (const float*)d_in[17];
    const float* Ws1  = (const float*)d_in[18]; const float* bs1 = (const float*)d_in[19];
    const float* Ws2  = (const float*)d_in[20]; const float* bs2 = (const float*)d_in[21];
    const float* Wfc1 = (const float*)d_in[22]; const float* bfc1= (const float*)d_in[23];
    const float* Wfc2 = (const float*)d_in[24]; const float* bfc2= (const float*)d_in[25];
    const float* Wtw  = (const float*)d_in[26]; const float* btw = (const float*)d_in[27];
    const float* Wmid = (const float*)d_in[28]; const float* bmid= (const float*)d_in[29];
    const float* Wbot = (const float*)d_in[30]; const float* bbot= (const float*)d_in[31];
    const float* Wconv= (const float*)d_in[32]; const float* bconv=(const float*)d_in[33];

    float* out = (float*)d_out;
    float* ws  = (float*)d_ws;

    const size_t N128 = (size_t)N_NODES * 128;
    const size_t BF128 = (size_t)NPAD * 128 / 2;   // bf16 [NPAD][128] in float units

    size_t off = 0;
    auto alloc = [&](size_t n) { float* p = ws + off; off += (n + 15) & ~size_t(15); return p; };
    float* QB1  = alloc(BF128);               // bf16 [NPAD][128]
    float* KB1  = alloc(BF128);
    float* VTB1 = alloc(BF128);               // bf16 [128][NPAD]
    float* XB   = alloc((size_t)NPAD * 256);  // bf16 [NPAD][512]
    float* WT1  = alloc(4 * 128 * 512 / 2);   // bf16 [4][128][512]
    float* WT2  = alloc(4 * 64 * 128 / 2);    // bf16 [4][64][128]
    float* WST1 = alloc(128 * 256 / 2);       // bf16 [128][256]
    float* WST2 = alloc(64 * 128 / 2);        // bf16 [64][128]
    float* AR1  = alloc((size_t)NPAD * 128);  // bf16 [NPAD][256] = [G|R]
    float* S1B  = alloc((size_t)NPAD * 64);   // bf16 [NPAD][128]
    float* H1   = alloc(N128);                // f32
    float* S2   = alloc(N128);                // f32 [N][64] (only N*64 used)
    float* DINV = alloc(N_NODES);
    int*   DEGI   = (int*)alloc(8008);
    int*   ROWPTR = (int*)alloc(8008);
    int*   CURSOR = (int*)alloc(8008);
    int2*  CSR    = (int2*)alloc(2 * (size_t)E_EDGES);
    float* PO   = alloc((size_t)NSPLIT * NQTOT * 128 / 2);  // bf16 partials
    float* PL   = alloc((size_t)NSPLIT * NQTOT);
    float* WVP  = alloc(6400);
    float* WV   = alloc(6400);
    float* MIDAVG = alloc(64);
    float* BOTW   = alloc(64);
    // layer-2 aliases over dead layer-1 buffers
    float* QB2  = QB1;
    float* KB2  = KB1;
    float* VTB2 = VTB1;
    float* H2   = H1;
    float* AR2  = AR1;

    // prep: degree count + x cast + all weight transposes (one kernel)
    hipMemsetAsync(DEGI, 0, N_NODES * sizeof(int), stream);
    prep_all<<<3945, 256, 0, stream>>>(
        x, ei, Wq1, Wk1, Wv1, Wg1, Wq2, Wk2, Wv2, Wg2, Ws1, Ws2,
        DEGI, (u16*)XB, (u16*)WT1, (u16*)WT2, (u16*)WST1, (u16*)WST2);
    prefix_rowptr<<<1, 256, 0, stream>>>(DEGI, ROWPTR, CURSOR, DINV);
    csr_fill<<<(E_EDGES + 255) / 256, 256, 0, stream>>>(ei, DINV, CURSOR, CSR);

    // ---- layer 1 ----
    proj4_mfma<512, 128><<<NPAD / 32, 256, 0, stream>>>(
        (const u16*)XB, (const u16*)WT1, bq1, bk1, bv1,
        (u16*)QB1, (u16*)KB1, (u16*)VTB1, H1);

    attn_split<128, NSPLIT><<<dim3(NSPLIT, 63), 256, 0, stream>>>(
        (const u16*)QB1, (const u16*)KB1, (const u16*)VTB1, (u16*)PO, PL);

    {
        int mb = (NPAD * 32) / 256, gb = (N_NODES * 32 + 255) / 256;
        merge_gather<128, NSPLIT><<<mb + gb, 256, 0, stream>>>(
            (const u16*)PO, PL, H1, ROWPTR, CSR, DINV, bg1, (u16*)AR1);
    }

    s_gemm_mfma<256, 128, 1, 4><<<NPAD / 32, 256, 0, stream>>>(
        (const u16*)AR1, (const u16*)WST1, bs1, (u16*)S1B);

    // ---- layer 2 ----
    proj4_mfma<128, 64><<<NPAD / 32, 256, 0, stream>>>(
        (const u16*)S1B, (const u16*)WT2, bq2, bk2, bv2,
        (u16*)QB2, (u16*)KB2, (u16*)VTB2, H2);

    attn_split<64, NSPLIT><<<dim3(NSPLIT, 63), 256, 0, stream>>>(
        (const u16*)QB2, (const u16*)KB2, (const u16*)VTB2, (u16*)PO, PL);

    {
        int mb = (NPAD * 16) / 256, gb = (N_NODES * 16 + 255) / 256;
        merge_gather<64, NSPLIT><<<mb + gb, 256, 0, stream>>>(
            (const u16*)PO, PL, H2, ROWPTR, CSR, DINV, bg2, (u16*)AR2);
    }

    s_gemm_mfma<128, 64, 0, 2><<<NPAD / 32, 128, 0, stream>>>(
        (const u16*)AR2, (const u16*)WST2, bs2, S2);

    // ---- head ----
    conv_wv<<<400, 256, 0, stream>>>(S2, Wconv, bconv, WVP);
    wv_copy<<<107, 256, 0, stream>>>(WVP, S2, WV, out);
    tree_bottom_kernel<<<400, 256, 0, stream>>>(S2, WV, out + 109072);
    col_mean2<<<128, 256, 0, stream>>>(S2, out + 109072, MIDAVG, BOTW);
    head_kernel<<<1, 64, 0, stream>>>(S2, MIDAVG, BOTW, Wtw, btw, Wmid, bmid,
                                      Wbot, bbot, Wfc1, bfc1, Wfc2, bfc2, out);
}